// Round 1
// baseline (1267.227 us; speedup 1.0000x reference)
//
#include <hip/hip_runtime.h>
#include <math.h>

#define EPSF 1e-5f

// ---- helpers ----------------------------------------------------------

__device__ __forceinline__ float dot16(const float4* r, const float* q) {
    float4 a = r[0], b = r[1], c = r[2], d = r[3];
    return a.x*q[0] + a.y*q[1] + a.z*q[2] + a.w*q[3]
         + b.x*q[4] + b.y*q[5] + b.z*q[6] + b.w*q[7]
         + c.x*q[8] + c.y*q[9] + c.z*q[10] + c.w*q[11]
         + d.x*q[12] + d.y*q[13] + d.z*q[14] + d.w*q[15];
}

// dot of a 128-float global row (64B-aligned) with 128 floats in LDS
__device__ __forceinline__ float dot128(const float* __restrict__ w, const float* x) {
    const float4* wr = (const float4*)w;
    const float4* xr = (const float4*)x;
    float s = 0.f;
#pragma unroll
    for (int i = 0; i < 32; i++) {
        float4 a = wr[i], b = xr[i];
        s += a.x*b.x + a.y*b.y + a.z*b.z + a.w*b.w;
    }
    return s;
}

// LayerNorm over 128 values held one-per-thread by threads 0..127.
// Must be called by ALL 256 threads. Returns (y-mean)/sqrt(var+eps).
__device__ __forceinline__ float ln_norm(float y, bool valid, int tid, float* part) {
    float s = valid ? y : 0.f;
#pragma unroll
    for (int off = 32; off >= 1; off >>= 1) s += __shfl_xor(s, off);
    __syncthreads();                 // protect 'part' from previous use
    if ((tid & 63) == 0) part[tid >> 6] = s;
    __syncthreads();
    float mean = (part[0] + part[1] + part[2] + part[3]) * (1.0f / 128.0f);
    float d = valid ? (y - mean) : 0.f;
    float ss = d * d;
#pragma unroll
    for (int off = 32; off >= 1; off >>= 1) ss += __shfl_xor(ss, off);
    __syncthreads();
    if ((tid & 63) == 0) part[tid >> 6] = ss;
    __syncthreads();
    float var = (part[0] + part[1] + part[2] + part[3]) * (1.0f / 128.0f);
    return (y - mean) * rsqrtf(var + EPSF);
}

// ---- kernel 1: k/v projection + self-attention + W0sa + LN ------------
// NOTE reference does a RAW reshape [B,S,E]->[B*H,S,HD]: head h of batch b
// attends over rows j = h*512 + s2 of K_sa[b] viewed as [4096][16].
// Rows j >= 4088 come from the newly appended k_sa/v_sa (head 7 only).

__global__ __launch_bounds__(256) void k_self(
    const float* __restrict__ h_t,
    const float* __restrict__ Kp, const float* __restrict__ Vp,   // [B,511,128]
    const float* __restrict__ Wk_w, const float* __restrict__ Wk_b,
    const float* __restrict__ Wv_w, const float* __restrict__ Wv_b,
    const float* __restrict__ W0_w, const float* __restrict__ W0_b,
    const float* __restrict__ ln_g, const float* __restrict__ ln_b,
    float* __restrict__ h1out)
{
    const int b = blockIdx.x, tid = threadIdx.x;
    __shared__ __align__(16) float sh_ht[128];
    __shared__ __align__(16) float sh_kv[256];   // [0..127]=k_sa, [128..255]=v_sa
    __shared__ __align__(16) float sh_O[128];
    __shared__ float part[4];

    if (tid < 128) sh_ht[tid] = h_t[(size_t)b * 128 + tid];
    __syncthreads();

    // k_sa (threads 0..127) / v_sa (threads 128..255): y[f] = b[f] + sum_e ht[e]*W[f,e]
    {
        const int f = tid & 127;
        const float* W = (tid < 128) ? Wk_w : Wv_w;
        float s = (tid < 128) ? Wk_b[f] : Wv_b[f];
        s += dot128(W + (size_t)f * 128, sh_ht);
        sh_kv[tid] = s;
    }
    __syncthreads();

    const int h = tid >> 5, l = tid & 31;
    float q[16];
#pragma unroll
    for (int d = 0; d < 16; d++) q[d] = sh_ht[h * 16 + d];

    const float* Kb = Kp + (size_t)b * (511 * 128);
    const float* Vb = Vp + (size_t)b * (511 * 128);

    // pass 1: scores (16 keys per lane, rows j = h*512 + l + 32k)
    float sc[16];
#pragma unroll
    for (int k = 0; k < 16; k++) {
        int j = h * 512 + l + 32 * k;
        float d;
        if (j < 4088) d = dot16((const float4*)(Kb + (size_t)j * 16), q);
        else          d = dot16((const float4*)(sh_kv + (j - 4088) * 16), q);
        sc[k] = 0.25f * d;
    }
    // group softmax (32 lanes per head; xor<32 stays inside the group)
    float m = sc[0];
#pragma unroll
    for (int k = 1; k < 16; k++) m = fmaxf(m, sc[k]);
#pragma unroll
    for (int off = 16; off >= 1; off >>= 1) m = fmaxf(m, __shfl_xor(m, off));
    float den = 0.f;
#pragma unroll
    for (int k = 0; k < 16; k++) { sc[k] = __expf(sc[k] - m); den += sc[k]; }
#pragma unroll
    for (int off = 16; off >= 1; off >>= 1) den += __shfl_xor(den, off);
    const float invd = 1.0f / den;

    // pass 2: O[h][d] = sum p * V-row
    float acc[16];
#pragma unroll
    for (int d = 0; d < 16; d++) acc[d] = 0.f;
#pragma unroll
    for (int k = 0; k < 16; k++) {
        int j = h * 512 + l + 32 * k;
        float p = sc[k] * invd;
        const float4* vr;
        if (j < 4088) vr = (const float4*)(Vb + (size_t)j * 16);
        else          vr = (const float4*)(sh_kv + 128 + (j - 4088) * 16);
        float4 v0 = vr[0], v1 = vr[1], v2 = vr[2], v3 = vr[3];
        acc[0] += p * v0.x; acc[1] += p * v0.y; acc[2]  += p * v0.z; acc[3]  += p * v0.w;
        acc[4] += p * v1.x; acc[5] += p * v1.y; acc[6]  += p * v1.z; acc[7]  += p * v1.w;
        acc[8] += p * v2.x; acc[9] += p * v2.y; acc[10] += p * v2.z; acc[11] += p * v2.w;
        acc[12]+= p * v3.x; acc[13]+= p * v3.y; acc[14] += p * v3.z; acc[15] += p * v3.w;
    }
#pragma unroll
    for (int off = 16; off >= 1; off >>= 1)
#pragma unroll
        for (int d = 0; d < 16; d++) acc[d] += __shfl_xor(acc[d], off);
    if (l == 0) {
#pragma unroll
        for (int d = 0; d < 16; d++) sh_O[h * 16 + d] = acc[d];
    }
    __syncthreads();

    // epilogue: y = h_t + W0sa(a_sa); LN(ln_sa)
    const bool valid = tid < 128;
    float y = 0.f;
    if (valid)
        y = sh_ht[tid] + W0_b[tid] + dot128(W0_w + (size_t)tid * 128, sh_O);
    float n = ln_norm(y, valid, tid, part);
    if (valid)
        h1out[(size_t)b * 128 + tid] = n * ln_g[tid] + ln_b[tid];
}

// ---- kernel 2: q-proj + masked enc-dec attention + W0att + LN + FFN + LN

__global__ __launch_bounds__(256) void k_enc(
    const float* __restrict__ h1,
    const float* __restrict__ Kp, const float* __restrict__ Vp,   // [B,1001,128]
    const int*   __restrict__ mask,                                // [B,1001]
    const float* __restrict__ Wq_w, const float* __restrict__ Wq_b,
    const float* __restrict__ W0_w, const float* __restrict__ W0_b,
    const float* __restrict__ W1_w, const float* __restrict__ W1_b,
    const float* __restrict__ W2_w, const float* __restrict__ W2_b,
    const float* __restrict__ gsa, const float* __restrict__ bsa,
    const float* __restrict__ gff, const float* __restrict__ bff,
    float* __restrict__ out)
{
    const int b = blockIdx.x, tid = threadIdx.x;
    __shared__ __align__(16) float sh_h[128];   // h1 (residual)
    __shared__ __align__(16) float sh_q[128];   // q, later reused for h2
    __shared__ __align__(16) float sh_O[128];
    __shared__ __align__(16) float sh_z[128];
    __shared__ float part[4];

    if (tid < 128) sh_h[tid] = h1[(size_t)b * 128 + tid];
    __syncthreads();
    if (tid < 128) sh_q[tid] = Wq_b[tid] + dot128(Wq_w + (size_t)tid * 128, sh_h);
    __syncthreads();

    const int h = tid >> 5, l = tid & 31;
    float q[16];
#pragma unroll
    for (int d = 0; d < 16; d++) q[d] = sh_q[h * 16 + d];

    const float* Kb = Kp + (size_t)b * (1001 * 128);
    const float* Vb = Vp + (size_t)b * (1001 * 128);
    const int*   mb = mask + (size_t)b * 1001;

    // pass 1: scores. Head h attends rows j = h*1001 + s2 of K_att[b] as [8008][16].
    // Masked keys are exactly -1e9 (pre-softmax) per reference; skip their loads.
    float sc[32];
#pragma unroll
    for (int k = 0; k < 32; k++) {
        int s2 = l + 32 * k;
        float v = -3.0e38f;                     // out-of-range -> exp==0
        if (s2 < 1001) {
            if (mb[s2] != 0) v = -1e9f;
            else v = 0.25f * dot16((const float4*)(Kb + (size_t)(h * 1001 + s2) * 16), q);
        }
        sc[k] = v;
    }
    float m = sc[0];
#pragma unroll
    for (int k = 1; k < 32; k++) m = fmaxf(m, sc[k]);
#pragma unroll
    for (int off = 16; off >= 1; off >>= 1) m = fmaxf(m, __shfl_xor(m, off));
    float den = 0.f;
#pragma unroll
    for (int k = 0; k < 32; k++) { sc[k] = __expf(sc[k] - m); den += sc[k]; }
#pragma unroll
    for (int off = 16; off >= 1; off >>= 1) den += __shfl_xor(den, off);
    const float invd = 1.0f / den;

    // pass 2 (skip p==0 rows: masked keys underflow to exactly 0 unless all masked,
    // in which case reference also gives uniform weights over masked rows)
    float acc[16];
#pragma unroll
    for (int d = 0; d < 16; d++) acc[d] = 0.f;
#pragma unroll
    for (int k = 0; k < 32; k++) {
        float p = sc[k] * invd;
        if (p != 0.f) {
            int s2 = l + 32 * k;
            const float4* vr = (const float4*)(Vb + (size_t)(h * 1001 + s2) * 16);
            float4 v0 = vr[0], v1 = vr[1], v2 = vr[2], v3 = vr[3];
            acc[0] += p * v0.x; acc[1] += p * v0.y; acc[2]  += p * v0.z; acc[3]  += p * v0.w;
            acc[4] += p * v1.x; acc[5] += p * v1.y; acc[6]  += p * v1.z; acc[7]  += p * v1.w;
            acc[8] += p * v2.x; acc[9] += p * v2.y; acc[10] += p * v2.z; acc[11] += p * v2.w;
            acc[12]+= p * v3.x; acc[13]+= p * v3.y; acc[14] += p * v3.z; acc[15] += p * v3.w;
        }
    }
#pragma unroll
    for (int off = 16; off >= 1; off >>= 1)
#pragma unroll
        for (int d = 0; d < 16; d++) acc[d] += __shfl_xor(acc[d], off);
    if (l == 0) {
#pragma unroll
        for (int d = 0; d < 16; d++) sh_O[h * 16 + d] = acc[d];
    }
    __syncthreads();

    const bool valid = tid < 128;

    // h = h1 + W0att(a); LN with ln_sa params (reference reuses ln_sa here)
    float y = 0.f;
    if (valid)
        y = sh_h[tid] + W0_b[tid] + dot128(W0_w + (size_t)tid * 128, sh_O);
    float n = ln_norm(y, valid, tid, part);
    float h2 = 0.f;
    if (valid) h2 = n * gsa[tid] + bsa[tid];
    __syncthreads();
    if (valid) sh_q[tid] = h2;       // reuse sh_q for h2
    __syncthreads();

    // FFN: z = relu(W1 h2 + b1); y2 = h2 + W2 z + b2; LN(ln_ff)
    float z = 0.f;
    if (valid) {
        z = W1_b[tid] + dot128(W1_w + (size_t)tid * 128, sh_q);
        z = fmaxf(z, 0.f);
    }
    __syncthreads();
    if (valid) sh_z[tid] = z;
    __syncthreads();
    float y2 = 0.f;
    if (valid)
        y2 = sh_q[tid] + W2_b[tid] + dot128(W2_w + (size_t)tid * 128, sh_z);
    float n2 = ln_norm(y2, valid, tid, part);
    if (valid)
        out[(size_t)b * 128 + tid] = n2 * gff[tid] + bff[tid];
}

// ---- launch -----------------------------------------------------------

extern "C" void kernel_launch(void* const* d_in, const int* in_sizes, int n_in,
                              void* d_out, int out_size, void* d_ws, size_t ws_size,
                              hipStream_t stream) {
    const float* h_t      = (const float*)d_in[0];
    const float* K_att    = (const float*)d_in[1];
    const float* V_att    = (const float*)d_in[2];
    const float* K_sa     = (const float*)d_in[3];
    const float* V_sa     = (const float*)d_in[4];
    const int*   mask     = (const int*)  d_in[5];
    const float* Wk_w     = (const float*)d_in[6];
    const float* Wk_b     = (const float*)d_in[7];
    const float* Wv_w     = (const float*)d_in[8];
    const float* Wv_b     = (const float*)d_in[9];
    const float* W0sa_w   = (const float*)d_in[10];
    const float* W0sa_b   = (const float*)d_in[11];
    const float* Wq_w     = (const float*)d_in[12];
    const float* Wq_b     = (const float*)d_in[13];
    const float* W0att_w  = (const float*)d_in[14];
    const float* W0att_b  = (const float*)d_in[15];
    const float* W1_w     = (const float*)d_in[16];
    const float* W1_b     = (const float*)d_in[17];
    const float* W2_w     = (const float*)d_in[18];
    const float* W2_b     = (const float*)d_in[19];
    const float* ln_sa_g  = (const float*)d_in[20];
    const float* ln_sa_b  = (const float*)d_in[21];
    const float* ln_ff_g  = (const float*)d_in[22];
    const float* ln_ff_b  = (const float*)d_in[23];

    float* out = (float*)d_out;
    float* h1  = (float*)d_ws;      // 1024*128 floats = 512 KB scratch

    k_self<<<dim3(1024), dim3(256), 0, stream>>>(
        h_t, K_sa, V_sa, Wk_w, Wk_b, Wv_w, Wv_b, W0sa_w, W0sa_b,
        ln_sa_g, ln_sa_b, h1);
    k_enc<<<dim3(1024), dim3(256), 0, stream>>>(
        h1, K_att, V_att, mask, Wq_w, Wq_b, W0att_w, W0att_b,
        W1_w, W1_b, W2_w, W2_b, ln_sa_g, ln_sa_b, ln_ff_g, ln_ff_b, out);
}